// Round 1
// baseline (376.296 us; speedup 1.0000x reference)
//
#include <hip/hip_runtime.h>

// LoRAConnector: B=4, T=2048, N=4, C=1024, A=8, nC=4096, SINKHORN_ITERS=20
//
// Round 2: attack the latency bottleneck.
//  Evidence: VALUBusy 12%, HBM 14%, occupancy 20%, VGPR=88 -> compiler had no
//  registers to keep phi loads in flight; ~400 L2 hits/thread fully serialized.
//  Change: depth-3 software pipeline over the 64 (m,e) steps. Triple-buffered
//  6-float4 phi group (bpp/bpo/bpr), consume group t while t+1,t+2 in flight,
//  issue t+3 after consumption. x loaded once in the prologue (anchored by the
//  sumsq pass so the 16 loads issue back-to-back), w prefetched one tile ahead.
//  __launch_bounds__(256,2) unlocks the VGPRs (expect ~190, 8 waves/CU).
//  All waitcnts remain compiler-generated dataflow waits -> no race surface.
//  FP accumulation order identical to the previous passing kernel.

#define BT 8192        // B*T tokens
#define NC 4096        // N*C
#define NC4 1024       // NC/4

__global__ __launch_bounds__(256, 2) void lora_connector_kernel(
    const float* __restrict__ x,
    const float* __restrict__ inw,
    const float* __restrict__ phi_pre,
    const float* __restrict__ phi_post,
    const float* __restrict__ phi_res,
    const float* __restrict__ b_pre,
    const float* __restrict__ b_post,
    const float* __restrict__ b_res,
    const float* __restrict__ alpha_pre,
    const float* __restrict__ alpha_post,
    const float* __restrict__ alpha_res,
    const int*   __restrict__ adapter_indices,
    float* __restrict__ out)
{
    const int tid = threadIdx.x;
    const int g   = tid & 3;        // which of the block's 4 tokens
    const int l   = tid >> 2;       // d4-slice 0..63
    const int tok = blockIdx.x * 4 + g;
    const int b   = blockIdx.x >> 9;          // tok / 2048, block-uniform
    const int idx = adapter_indices[b];

    const float4* __restrict__ x4p = (const float4*)x + (size_t)tok * NC4;
    const float4* __restrict__ w4p = (const float4*)inw + (size_t)idx * NC4;
    const float4* __restrict__ pp4 = (const float4*)(phi_pre  + (size_t)idx * (NC * 4));
    const float4* __restrict__ po4 = (const float4*)(phi_post + (size_t)idx * (NC * 4));
    const float4* __restrict__ pr4 = (const float4*)(phi_res  + (size_t)idx * (NC * 16));

    // ---- Prologue: issue all 16 x loads (sumsq pass anchors them early) ----
    float4 xs[16];
    #pragma unroll
    for (int m = 0; m < 16; ++m) xs[m] = x4p[m * 64 + l];

    float4 wreg[2];
    wreg[0] = w4p[l];
    int wOff = 64 + l;               // next w tile to prefetch

    // phi group offsets (float4 units); advance per tile
    int ppOff = l * 4;               // pp4/po4 index for (m, e=0)
    int prOff = l * 16;              // pr4 index for (m, e=0, q=0)

    // ---- Prime the pipeline: groups t=0,1,2 (m=0, e=0..2) ----
    float4 bpp[3], bpo[3], bpr[3][4];
    #pragma unroll
    for (int p = 0; p < 3; ++p) {
        bpp[p] = pp4[ppOff + p];
        bpo[p] = po4[ppOff + p];
        #pragma unroll
        for (int q = 0; q < 4; ++q) bpr[p][q] = pr4[prOff + p * 4 + q];
    }

    float acc[25];
    #pragma unroll
    for (int j = 0; j < 24; ++j) acc[j] = 0.0f;

    // sumsq over xs (same m-ascending chain order as before)
    {
        float ssum = 0.0f;
        #pragma unroll
        for (int m = 0; m < 16; ++m) {
            const float4 v = xs[m];
            ssum = fmaf(v.x, v.x, fmaf(v.y, v.y, fmaf(v.z, v.z, fmaf(v.w, v.w, ssum))));
        }
        acc[24] = ssum;
    }

    // ---- Phase 1: depth-3 pipelined stream over 64 (m,e) steps ----
    float4 xw = {0.0f, 0.0f, 0.0f, 0.0f};
    #pragma unroll
    for (int t = 0; t < 64; ++t) {
        const int m  = t >> 2;
        const int e  = t & 3;
        const int sl = t % 3;

        if (e == 0) {
            const float4 xv = xs[m];
            const float4 wv = wreg[m & 1];
            xw.x = xv.x * wv.x; xw.y = xv.y * wv.y;
            xw.z = xv.z * wv.z; xw.w = xv.w * wv.w;
            if (m < 15) {                      // prefetch w one full tile ahead
                wreg[(m + 1) & 1] = w4p[wOff];
                wOff += 64;
            }
        }
        const float s = (e == 0) ? xw.x : (e == 1) ? xw.y : (e == 2) ? xw.z : xw.w;

        // consume group t (buffers sl); groups t+1, t+2 remain in flight
        const float4 a = bpp[sl];
        acc[0] = fmaf(s, a.x, acc[0]); acc[1] = fmaf(s, a.y, acc[1]);
        acc[2] = fmaf(s, a.z, acc[2]); acc[3] = fmaf(s, a.w, acc[3]);
        const float4 p = bpo[sl];
        acc[4] = fmaf(s, p.x, acc[4]); acc[5] = fmaf(s, p.y, acc[5]);
        acc[6] = fmaf(s, p.z, acc[6]); acc[7] = fmaf(s, p.w, acc[7]);
        #pragma unroll
        for (int q = 0; q < 4; ++q) {
            const float4 r = bpr[sl][q];
            acc[8 + q * 4 + 0] = fmaf(s, r.x, acc[8 + q * 4 + 0]);
            acc[8 + q * 4 + 1] = fmaf(s, r.y, acc[8 + q * 4 + 1]);
            acc[8 + q * 4 + 2] = fmaf(s, r.z, acc[8 + q * 4 + 2]);
            acc[8 + q * 4 + 3] = fmaf(s, r.w, acc[8 + q * 4 + 3]);
        }

        // issue group t+3 into the slot just consumed
        if (t < 61) {
            const int en = (e + 3) & 3;        // (t+3)&3; for e==0 this is 3 (old tile)
            bpp[sl] = pp4[ppOff + en];
            bpo[sl] = po4[ppOff + en];
            #pragma unroll
            for (int q = 0; q < 4; ++q) bpr[sl][q] = pr4[prOff + en * 4 + q];
        }
        if (e == 0) {                          // after the old-tile e=3 issue
            ppOff += 256;
            prOff += 1024;
        }
    }

    // ---- Phase 2a: intra-wave butterfly over lane bits 2..5 (16 slices/token) ----
    #pragma unroll
    for (int j = 0; j < 25; ++j) {
        float v = acc[j];
        v += __shfl_xor(v, 4);
        v += __shfl_xor(v, 8);
        v += __shfl_xor(v, 16);
        v += __shfl_xor(v, 32);
        acc[j] = v;
    }

    // ---- Phase 2b: cross-wave reduction via LDS ----
    __shared__ float red[4][4][26];
    const int wv = tid >> 6;
    const int lw = tid & 63;
    if ((lw >> 2) == 0) {            // lanes 0..3: lane == g
        #pragma unroll
        for (int j = 0; j < 25; ++j) red[wv][g][j] = acc[j];
    }
    __syncthreads();
    float tot[25];
    #pragma unroll
    for (int j = 0; j < 25; ++j)
        tot[j] = (red[0][g][j] + red[1][g][j]) + (red[2][g][j] + red[3][g][j]);

    // ---- Phase 2c: rms, gates, sinkhorn ----
    const float inv_rms = rsqrtf(tot[24] * (1.0f / 4096.0f) + 1e-5f);
    const float apre  = alpha_pre[idx];
    const float apost = alpha_post[idx];
    const float ares  = alpha_res[idx];

    float Hpre[4], Hpost[4];
    #pragma unroll
    for (int n = 0; n < 4; ++n) {
        const float zp = fmaf(apre,  tot[n]     * inv_rms, b_pre[idx * 4 + n]);
        Hpre[n]  = 1.0f / (1.0f + __expf(-zp));
        const float zq = fmaf(apost, tot[4 + n] * inv_rms, b_post[idx * 4 + n]);
        Hpost[n] = 2.0f / (1.0f + __expf(-zq));
    }

    // lane owns element (si,sj) of token g's 4x4 matrix
    const int s16 = lw >> 2;         // 0..15
    const int sj = s16 & 3;
    const int si = s16 >> 2;
    float Mv = __expf(fmaf(ares, tot[8 + si * 4 + sj] * inv_rms,
                           b_res[idx * 16 + si * 4 + sj]));
    #pragma unroll
    for (int it = 0; it < 20; ++it) {
        float rs = Mv + __shfl_xor(Mv, 4);   // sum over j (lane bits 2,3)
        rs += __shfl_xor(rs, 8);
        Mv *= __builtin_amdgcn_rcpf(rs);
        float cs = Mv + __shfl_xor(Mv, 16);  // sum over i (lane bits 4,5)
        cs += __shfl_xor(cs, 32);
        Mv *= __builtin_amdgcn_rcpf(cs);
    }

    // gather full W[i][j] = M[i][j] + Hpost[i]*Hpre[j] for this thread's token
    float W[4][4];
    #pragma unroll
    for (int ss = 0; ss < 16; ++ss) {
        const float mm = __shfl(Mv, ss * 4 + g);
        W[ss >> 2][ss & 3] = fmaf(Hpost[ss >> 2], Hpre[ss & 3], mm);
    }

    // ---- Phase 3: out[i,c] = sum_j W[i][j] * x[j,c], all from registers ----
    float4* __restrict__ out4 = (float4*)out + (size_t)tok * NC4;
    #pragma unroll
    for (int k = 0; k < 4; ++k) {
        const int c4 = k * 64 + l;
        const float4 x0 = xs[0 * 4 + k];
        const float4 x1 = xs[1 * 4 + k];
        const float4 x2 = xs[2 * 4 + k];
        const float4 x3 = xs[3 * 4 + k];
        #pragma unroll
        for (int i = 0; i < 4; ++i) {
            float4 o;
            o.x = fmaf(W[i][0], x0.x, fmaf(W[i][1], x1.x, fmaf(W[i][2], x2.x, W[i][3] * x3.x)));
            o.y = fmaf(W[i][0], x0.y, fmaf(W[i][1], x1.y, fmaf(W[i][2], x2.y, W[i][3] * x3.y)));
            o.z = fmaf(W[i][0], x0.z, fmaf(W[i][1], x1.z, fmaf(W[i][2], x2.z, W[i][3] * x3.z)));
            o.w = fmaf(W[i][0], x0.w, fmaf(W[i][1], x1.w, fmaf(W[i][2], x2.w, W[i][3] * x3.w)));
            out4[i * 256 + c4] = o;
        }
    }
}

extern "C" void kernel_launch(void* const* d_in, const int* in_sizes, int n_in,
                              void* d_out, int out_size, void* d_ws, size_t ws_size,
                              hipStream_t stream) {
    const float* x         = (const float*)d_in[0];
    const float* inw       = (const float*)d_in[1];
    const float* phi_pre   = (const float*)d_in[2];
    const float* phi_post  = (const float*)d_in[3];
    const float* phi_res   = (const float*)d_in[4];
    const float* b_pre     = (const float*)d_in[5];
    const float* b_post    = (const float*)d_in[6];
    const float* b_res     = (const float*)d_in[7];
    const float* alpha_pre = (const float*)d_in[8];
    const float* alpha_post= (const float*)d_in[9];
    const float* alpha_res = (const float*)d_in[10];
    const int*   adapter   = (const int*)d_in[11];
    float* out = (float*)d_out;

    dim3 grid(BT / 4);   // 2048 blocks, 4 tokens each
    dim3 block(256);
    lora_connector_kernel<<<grid, block, 0, stream>>>(
        x, inw, phi_pre, phi_post, phi_res,
        b_pre, b_post, b_res,
        alpha_pre, alpha_post, alpha_res,
        adapter, out);
}